// Round 1
// baseline (880.217 us; speedup 1.0000x reference)
//
#include <hip/hip_runtime.h>
#include <math.h>

#define NCB 7
#define CBK 1024
#define CD  8
#define BB  16
#define DD  256
#define TT  8192

static constexpr size_t ZQN  = (size_t)BB * DD * TT;   // 33554432
static constexpr size_t IDX0 = ZQN + 2;

// ---------------------------------------------------------------- prep ------
// Normalizes weight-norm conv weights and codebooks into workspace.
// wTin [NCB][DD][CD], wTout [NCB][DD][CD], cbp [NCB][CBK][16] (8 cb_n + c2 + pad)
__global__ void rvq_prep(const float* __restrict__ in_v, const float* __restrict__ in_g,
                         const float* __restrict__ out_v, const float* __restrict__ out_g,
                         const float* __restrict__ cb,
                         float* __restrict__ wTin, float* __restrict__ wTout,
                         float* __restrict__ cbp, double* __restrict__ lossAcc)
{
#pragma clang fp contract(off)
  int gid = blockIdx.x * blockDim.x + threadIdx.x;
  if (gid == 0) *lossAcc = 0.0;
  if (gid < NCB*DD*CD) {
    int i = gid / (DD*CD); int rem = gid % (DD*CD); int d = rem / CD; int c = rem % CD;
    const float* vrow = in_v + ((size_t)i*CD + c) * DD;   // in_v [NCB][CD][DD]
    double acc = 0.0;
    for (int q = 0; q < DD; ++q) { double v = vrow[q]; acc += v*v; }
    float nf = (float)sqrt(acc);
    wTin[((size_t)i*DD + d)*CD + c] = (in_g[i*CD + c] * vrow[d]) / nf;
  } else if (gid < 2*NCB*DD*CD) {
    int e = gid - NCB*DD*CD;
    int i = e / (DD*CD); int rem = e % (DD*CD); int d = rem / CD; int c = rem % CD;
    const float* vrow = out_v + ((size_t)i*DD + d)*CD;    // out_v [NCB][DD][CD]
    double acc = 0.0;
    for (int q = 0; q < CD; ++q) { double v = vrow[q]; acc += v*v; }
    float nf = (float)sqrt(acc);
    wTout[((size_t)i*DD + d)*CD + c] = (out_g[i*DD + d] * vrow[c]) / nf;
  } else if (gid < 2*NCB*DD*CD + NCB*CBK) {
    int e = gid - 2*NCB*DD*CD;
    int i = e / CBK; int k = e % CBK;
    const float* row = cb + ((size_t)i*CBK + k)*CD;
    double acc = 0.0;
    for (int c = 0; c < CD; ++c) { double v = row[c]; acc += v*v; }
    float nf = fmaxf((float)sqrt(acc), 1e-12f);
    float* orow = cbp + ((size_t)i*CBK + k)*16;
    float c2 = 0.f;
    for (int c = 0; c < CD; ++c) {
      float cn = row[c] / nf;            // IEEE division, mirrors np
      orow[c] = cn;
      float q = cn*cn; c2 += q;          // square-then-add (contract off)
    }
    orow[8] = c2;
  }
}

// ---------------------------------------------------------------- main ------
// block = 256 threads (4 waves), 64 t-positions per block.
// Thread (wave wu, lane p) owns residual[d = wu*64 + j][t0+p], j=0..63, in VGPRs.
__launch_bounds__(256, 2)
__global__ void rvq_main(const float* __restrict__ z,
                         const float* __restrict__ in_b, const float* __restrict__ out_b,
                         const float* __restrict__ cb,
                         const int* __restrict__ nqp,
                         const float* __restrict__ wTin, const float* __restrict__ wTout,
                         const float* __restrict__ cbp,
                         float* __restrict__ out, double* __restrict__ lossAcc)
{
#pragma clang fp contract(off)
  const int tid = threadIdx.x;
  const int p   = tid & 63;
  const int wu  = __builtin_amdgcn_readfirstlane(tid >> 6);  // provably uniform -> s_loads
  const int blk = blockIdx.x;
  const int b   = blk >> 7;            // 128 t-tiles per batch
  const int t0  = (blk & 127) << 6;
  int nq = *nqp; nq = nq < 0 ? 0 : (nq > NCB ? NCB : nq);

  __shared__ float zep[4][64][CD];   // per-wave z_e partials
  __shared__ float encn[64][CD];     // normalized encoding
  __shared__ float zef[64][CD];      // full z_e (for loss / STE)
  __shared__ float aval[64];         // sum(enc_n^2)
  __shared__ float bdist[4][64];     // per-wave best dist
  __shared__ int   bkix[4][64];      // per-wave best k
  __shared__ float zst[64][CD];      // z_q_ste

  const float* zbase = z + ((size_t)b*DD + wu*64)*TT + t0 + p;
  float* zqbase = out + ((size_t)b*DD + wu*64)*TT + t0 + p;

  float r[64];
#pragma unroll
  for (int j = 0; j < 64; ++j) r[j] = zbase[(size_t)j*TT];

  if (nq == 0) {
#pragma unroll 8
    for (int j = 0; j < 64; ++j) zqbase[(size_t)j*TT] = 0.f;
  }

  double lacc = 0.0;

  for (int i = 0; i < NCB; ++i) {
    // ---- 1. in-projection partials over this wave's 64-d slice (registers only)
    float ze[CD];
#pragma unroll
    for (int c = 0; c < CD; ++c) ze[c] = 0.f;
    const float* wrow = wTin + ((size_t)i*DD + wu*64)*CD;
#pragma unroll 8
    for (int j = 0; j < 64; ++j) {
      float rv = r[j];
#pragma unroll
      for (int c = 0; c < CD; ++c) ze[c] = fmaf(wrow[j*CD + c], rv, ze[c]);
    }
#pragma unroll
    for (int c = 0; c < CD; ++c) zep[wu][p][c] = ze[c];
    __syncthreads();

    // ---- 2. reduce partials + bias, l2-normalize (wave 0 only)
    if (tid < 64) {
      float zfull[CD];
#pragma unroll
      for (int c = 0; c < CD; ++c) {
        float s = ((zep[0][p][c] + zep[1][p][c]) + zep[2][p][c]) + zep[3][p][c];
        zfull[c] = s + in_b[i*CD + c];
      }
      float ss = 0.f;
#pragma unroll
      for (int c = 0; c < CD; ++c) { float q = zfull[c]*zfull[c]; ss += q; }
      float den = fmaxf(sqrtf(ss), 1e-12f);
      float a2 = 0.f;
#pragma unroll
      for (int c = 0; c < CD; ++c) {
        float en = zfull[c] / den;       // IEEE division, mirrors np
        encn[p][c] = en;
        zef[p][c]  = zfull[c];
        float q = en*en; a2 += q;
      }
      aval[p] = a2;
    }
    __syncthreads();

    // ---- 3. distance scan: each wave scans its 256-k quarter
    float en[CD];
#pragma unroll
    for (int c = 0; c < CD; ++c) en[c] = encn[p][c];
    float a2 = aval[p];
    const float* crow = cbp + ((size_t)i*CBK + wu*256)*16;
    float best = 3.0e38f; int bk = 0;
#pragma unroll 4
    for (int kk = 0; kk < 256; ++kk) {
      const float* rw = crow + kk*16;    // uniform -> s_load_dwordx16
      float m = en[0]*rw[0];
#pragma unroll
      for (int c = 1; c < CD; ++c) m = fmaf(en[c], rw[c], m);
      float dd = fmaf(-2.f, m, a2) + rw[8];  // == (a - 2m) + c2 with np rounding
      bool lt = dd < best;                    // strict: first-min tie-break
      best = lt ? dd : best;
      bk   = lt ? kk : bk;
    }
    bdist[wu][p] = best; bkix[wu][p] = wu*256 + bk;
    __syncthreads();

    // ---- 4. combine argmin, fetch raw codeword, STE, loss, index out (wave 0)
    if (tid < 64) {
      float bb_ = bdist[0][p]; int k = bkix[0][p];
#pragma unroll
      for (int ww = 1; ww < 4; ++ww) {          // ascending k-ranges, strict <
        float dv = bdist[ww][p]; int kv = bkix[ww][p];
        bool lt = dv < bb_;
        bb_ = lt ? dv : bb_;
        k   = lt ? kv : k;
      }
      const float* qrow = cb + ((size_t)i*CBK + k)*CD;   // raw codebook row
      float sloc = 0.f;
#pragma unroll
      for (int c = 0; c < CD; ++c) {
        float zc = qrow[c];
        float zv = zef[p][c];
        zst[p][c] = zv + (zc - zv);             // z_e + (z_q_c - z_e), np rounding
        float df = zv - zc;
        float q = df*df; sloc += q;
      }
      if (i < nq) lacc += (double)sloc;
      out[IDX0 + ((size_t)b*NCB + i)*TT + t0 + p] = (float)k;
    }
    __syncthreads();

    // ---- 5. out-projection + residual update (register residual)
    float zs[CD];
#pragma unroll
    for (int c = 0; c < CD; ++c) zs[c] = zst[p][c];
    const float* worow = wTout + ((size_t)i*DD + wu*64)*CD;
    const float* obrow = out_b + i*DD + wu*64;
#pragma unroll 8
    for (int j = 0; j < 64; ++j) {
      float m = worow[j*CD]*zs[0];
#pragma unroll
      for (int c = 1; c < CD; ++c) m = fmaf(worow[j*CD + c], zs[c], m);
      float zqi = m + obrow[j];
      r[j] -= zqi;
    }
    if (i == nq - 1) {                  // z_q = z - residual_after_nq
#pragma unroll 8
      for (int j = 0; j < 64; ++j)
        zqbase[(size_t)j*TT] = zbase[(size_t)j*TT] - r[j];
    }
    __syncthreads();
  }

  // ---- loss reduction: wave 0 holds all per-position partials
  if (tid < 64) {
#pragma unroll
    for (int off = 32; off >= 1; off >>= 1) lacc += __shfl_down(lacc, off, 64);
    if (p == 0) atomicAdd(lossAcc, lacc);
  }
}

// ------------------------------------------------------------- finalize -----
__global__ void rvq_fin(const double* __restrict__ lossAcc, float* __restrict__ out) {
  float v = (float)(*lossAcc * (1.0 / 1048576.0));  // / (CD*TT) / BB, 2^20 exact
  out[ZQN]     = v;   // commitment_loss
  out[ZQN + 1] = v;   // codebook_loss (bitwise identical in reference)
}

// ---------------------------------------------------------------- launch ----
extern "C" void kernel_launch(void* const* d_in, const int* in_sizes, int n_in,
                              void* d_out, int out_size, void* d_ws, size_t ws_size,
                              hipStream_t stream) {
  const float* z     = (const float*)d_in[0];
  const float* in_v  = (const float*)d_in[1];
  const float* in_g  = (const float*)d_in[2];
  const float* in_b  = (const float*)d_in[3];
  const float* out_v = (const float*)d_in[4];
  const float* out_g = (const float*)d_in[5];
  const float* out_b = (const float*)d_in[6];
  const float* cb    = (const float*)d_in[7];
  const int*   nqp   = (const int*)d_in[8];
  float* out = (float*)d_out;

  double* lossAcc = (double*)d_ws;
  float* wTin  = (float*)((char*)d_ws + 64);
  float* wTout = wTin  + (size_t)NCB*DD*CD;     // 14336 floats
  float* cbp   = wTout + (size_t)NCB*DD*CD;     // 14336 floats; cbp = 114688 floats

  rvq_prep<<<140, 256, 0, stream>>>(in_v, in_g, out_v, out_g, cb,
                                    wTin, wTout, cbp, lossAcc);
  rvq_main<<<BB * (TT/64), 256, 0, stream>>>(z, in_b, out_b, cb, nqp,
                                             wTin, wTout, cbp, out, lossAcc);
  rvq_fin<<<1, 1, 0, stream>>>(lossAcc, out);
}